// Round 1
// baseline (494.015 us; speedup 1.0000x reference)
//
#include <hip/hip_runtime.h>
#include <math.h>

namespace {

constexpr int kB = 64;
constexpr int kN = 4096;
constexpr int kM = 128;
constexpr int kH = 512;
constexpr int kE = 256;
constexpr int kO = 256;
constexpr int kGates = 4 * kH;       // 2048
constexpr int kCatW = 3 * kM + kH;   // 896  (read0|read1|read2|h)
constexpr int kPRow = 1600;          // padded 1572 (3*390 write + 3*134 read)
constexpr int kWN = kB * kN;

__device__ __forceinline__ float sigm_(float x) { return 1.f / (1.f + expf(-x)); }
__device__ __forceinline__ float softplus_(float x) { return x > 20.f ? x : log1pf(expf(x)); }

// ---------------- init: zero accumulators, bias-init output ----------------
__global__ __launch_bounds__(256) void init_ws_k(float* gates, float* praw, float* cat,
                                                 float* out, const float* __restrict__ out_b) {
  int idx = blockIdx.x * 256 + threadIdx.x;           // grid 512 -> 131072 threads
  if (idx < kB * kGates) gates[idx] = 0.f;
  if (idx < kB * kPRow)  praw[idx] = 0.f;
  if (idx < kB * 3 * kM) cat[(idx / 384) * kCatW + (idx % 384)] = 0.f;
  if (idx < kB * kO)     out[idx] = out_b[idx & (kO - 1)];
}

// ------- generic small GEMM: C[b, c0+j] += sum_{k in chunk} A[b,k]*W[j,k] -------
// grid: (ceil(J/64), K/128); block 256; K must be a multiple of 128.
__global__ __launch_bounds__(256) void gemm_tn(const float* __restrict__ A, int lda,
                                               const float* __restrict__ W, int ldw,
                                               float* __restrict__ C, int ldc, int c0, int J) {
  __shared__ float As[64][68];
  __shared__ float Ws[64][68];
  const int tid = threadIdx.x;
  const int j0 = blockIdx.x * 64;
  const int b0 = (tid & 15) * 4;
  const int j4 = (tid >> 4) * 4;
  float acc[4][4] = {};
  for (int kc = 0; kc < 2; kc++) {
    const int k0 = blockIdx.y * 128 + kc * 64;
    __syncthreads();
#pragma unroll
    for (int i = 0; i < 4; i++) {
      int idx = tid + i * 256;          // 0..1023
      int bb = idx >> 4;                // 0..63
      int kk = (idx & 15) * 4;          // 0..60
      float4 v = *(const float4*)(A + (size_t)bb * lda + k0 + kk);
      As[kk][bb] = v.x; As[kk + 1][bb] = v.y; As[kk + 2][bb] = v.z; As[kk + 3][bb] = v.w;
      float4 w = make_float4(0.f, 0.f, 0.f, 0.f);
      if (j0 + bb < J) w = *(const float4*)(W + (size_t)(j0 + bb) * ldw + k0 + kk);
      Ws[kk][bb] = w.x; Ws[kk + 1][bb] = w.y; Ws[kk + 2][bb] = w.z; Ws[kk + 3][bb] = w.w;
    }
    __syncthreads();
#pragma unroll 2
    for (int k = 0; k < 64; k++) {
      float4 av = *(const float4*)&As[k][b0];
      float4 wv = *(const float4*)&Ws[k][j4];
      float aa[4] = {av.x, av.y, av.z, av.w};
      float wwv[4] = {wv.x, wv.y, wv.z, wv.w};
#pragma unroll
      for (int ii = 0; ii < 4; ii++)
#pragma unroll
        for (int jj = 0; jj < 4; jj++) acc[ii][jj] += aa[ii] * wwv[jj];
    }
  }
#pragma unroll
  for (int ii = 0; ii < 4; ii++)
#pragma unroll
    for (int jj = 0; jj < 4; jj++) {
      int j = j0 + j4 + jj;
      if (j < J) atomicAdd(&C[(size_t)(b0 + ii) * ldc + c0 + j], acc[ii][jj]);
    }
}

// ---------------- LSTM nonlinearity: gates(+biases) -> h into cat[:,384:] ----------------
__global__ __launch_bounds__(256) void lstm_nl(const float* __restrict__ gates,
                                               const float* __restrict__ b_ih,
                                               const float* __restrict__ b_hh,
                                               const float* __restrict__ c_prev,
                                               float* __restrict__ cat) {
  int idx = blockIdx.x * 256 + threadIdx.x;
  if (idx >= kB * kH) return;
  int b = idx >> 9;
  int hh = idx & (kH - 1);
  const float* g = gates + (size_t)b * kGates;
  float i_ = g[hh]            + b_ih[hh]            + b_hh[hh];
  float f_ = g[kH + hh]       + b_ih[kH + hh]       + b_hh[kH + hh];
  float g_ = g[2 * kH + hh]   + b_ih[2 * kH + hh]   + b_hh[2 * kH + hh];
  float o_ = g[3 * kH + hh]   + b_ih[3 * kH + hh]   + b_hh[3 * kH + hh];
  float c = sigm_(f_) * c_prev[idx] + sigm_(i_) * tanhf(g_);
  float h = sigm_(o_) * tanhf(c);
  cat[(size_t)b * kCatW + 3 * kM + hh] = h;
}

// ---------------- split head params; apply biases + nonlinearities ----------------
// grid 64 (b), block 128 (m). scal[head][b][8] = {beta, g, r, s0, s1, s2, knorm, pad}
__global__ __launch_bounds__(128) void split_params(const float* __restrict__ praw,
                                                    const float* __restrict__ write_b,
                                                    const float* __restrict__ read_b,
                                                    float* __restrict__ kwb, float* __restrict__ krb,
                                                    float* __restrict__ evb, float* __restrict__ avb,
                                                    float* __restrict__ scal) {
  const int b = blockIdx.x;
  const int m = threadIdx.x;
  __shared__ float red[2];
  for (int i = 0; i < 3; i++) {  // write heads
    const float* p = praw + (size_t)b * kPRow + i * 390;
    const float* wb = write_b + i * 390;
    float kv = p[m] + wb[m];
    kwb[((size_t)i * kB + b) * kM + m] = kv;
    evb[((size_t)i * kB + b) * kM + m] = sigm_(p[134 + m] + wb[134 + m]);
    avb[((size_t)i * kB + b) * kM + m] = p[262 + m] + wb[262 + m];
    float sq = kv * kv;
#pragma unroll
    for (int mm = 1; mm < 64; mm <<= 1) sq += __shfl_xor(sq, mm, 64);
    __syncthreads();
    if ((m & 63) == 0) red[m >> 6] = sq;
    __syncthreads();
    if (m == 0) {
      float* s = scal + ((size_t)i * kB + b) * 8;
      s[0] = softplus_(p[128] + wb[128]);
      s[1] = sigm_(p[129] + wb[129]);
      s[2] = 1.f + softplus_(p[133] + wb[133]);
      float x0 = p[130] + wb[130], x1 = p[131] + wb[131], x2 = p[132] + wb[132];
      float mx = fmaxf(x0, fmaxf(x1, x2));
      float e0 = expf(x0 - mx), e1 = expf(x1 - mx), e2 = expf(x2 - mx);
      float si = 1.f / (e0 + e1 + e2);
      s[3] = e0 * si; s[4] = e1 * si; s[5] = e2 * si;
      s[6] = sqrtf(red[0] + red[1]);
    }
  }
  for (int i = 0; i < 3; i++) {  // read heads
    const float* p = praw + (size_t)b * kPRow + 1170 + i * 134;
    const float* rb = read_b + i * 134;
    float kv = p[m] + rb[m];
    krb[((size_t)i * kB + b) * kM + m] = kv;
    float sq = kv * kv;
#pragma unroll
    for (int mm = 1; mm < 64; mm <<= 1) sq += __shfl_xor(sq, mm, 64);
    __syncthreads();
    if ((m & 63) == 0) red[m >> 6] = sq;
    __syncthreads();
    if (m == 0) {
      float* s = scal + ((size_t)(3 + i) * kB + b) * 8;
      s[0] = softplus_(p[128] + rb[128]);
      s[1] = sigm_(p[129] + rb[129]);
      s[2] = 1.f + softplus_(p[133] + rb[133]);
      float x0 = p[130] + rb[130], x1 = p[131] + rb[131], x2 = p[132] + rb[132];
      float mx = fmaxf(x0, fmaxf(x1, x2));
      float e0 = expf(x0 - mx), e1 = expf(x1 - mx), e2 = expf(x2 - mx);
      float si = 1.f / (e0 + e1 + e2);
      s[3] = e0 * si; s[4] = e1 * si; s[5] = e2 * si;
      s[6] = sqrtf(red[0] + red[1]);
    }
  }
}

// ---------------- bank pass: recompute update chain, dots/norms, read accumulate ----------------
struct BankArgs {
  const float* bank;
  const float* cw[3];   // chain write weights (B,N)
  const float* ev[3];   // erase vectors (B,M)
  const float* av[3];   // add vectors (B,M)
  const float* rw[3];   // read weights applied after chain step j (B,N), or null
  float* ro[3];         // readout column base (row stride kCatW)
  const float* k1;      // score key 1 (B,M) or null
  const float* k2;      // score key 2 (B,M) or null
  float* s1; float* s2; float* ssq;  // (B,N) outputs
};

template <int NC>
__global__ __launch_bounds__(256) void bank_pass(BankArgs A) {
  const int b = blockIdx.y;
  const int tid = threadIdx.x;
  const int lane = tid & 63;
  const int wv = tid >> 6;
  const int sub = lane >> 4;       // row within the wave's 4-row group
  const int lm = lane & 15;
  const int m8 = lm * 8;
  constexpr int NCA = (NC > 0) ? NC : 1;
  float e_r[NCA][8], a_r[NCA][8];
#pragma unroll
  for (int j = 0; j < NC; j++)
#pragma unroll
    for (int t = 0; t < 8; t++) {
      e_r[j][t] = A.ev[j][b * kM + m8 + t];
      a_r[j][t] = A.av[j][b * kM + m8 + t];
    }
  const bool has1 = (A.s1 != nullptr);
  const bool has2 = (A.s2 != nullptr);
  float k1r[8] = {}, k2r[8] = {};
  if (has1) {
#pragma unroll
    for (int t = 0; t < 8; t++) k1r[t] = A.k1[b * kM + m8 + t];
  }
  if (has2) {
#pragma unroll
    for (int t = 0; t < 8; t++) k2r[t] = A.k2[b * kM + m8 + t];
  }
  float racc[3][8];
#pragma unroll
  for (int j = 0; j < 3; j++)
#pragma unroll
    for (int t = 0; t < 8; t++) racc[j][t] = 0.f;
  __shared__ float rlds[3][kM];
  if (tid < kM) { rlds[0][tid] = 0.f; rlds[1][tid] = 0.f; rlds[2][tid] = 0.f; }

  const size_t bbase = (size_t)b * kN * kM;
  const size_t brow = (size_t)b * kN;
  for (int it = 0; it < 16; it++) {
    const int row = blockIdx.x * 256 + it * 16 + wv * 4 + sub;
    const float* rp = A.bank + bbase + (size_t)row * kM + m8;
    float4 u0 = *(const float4*)rp;
    float4 u1 = *(const float4*)(rp + 4);
    float v[8] = {u0.x, u0.y, u0.z, u0.w, u1.x, u1.y, u1.z, u1.w};
#pragma unroll
    for (int j = 0; j < NC; j++) {
      const float wj = A.cw[j][brow + row];
#pragma unroll
      for (int t = 0; t < 8; t++) v[t] += wj * (a_r[j][t] - e_r[j][t] * v[t]);
      if (A.rw[j]) {
        const float rv = A.rw[j][brow + row];
#pragma unroll
        for (int t = 0; t < 8; t++) racc[j][t] += rv * v[t];
      }
    }
    if (has1) {
      float d1 = 0.f, d2 = 0.f, sq = 0.f;
#pragma unroll
      for (int t = 0; t < 8; t++) { d1 += v[t] * k1r[t]; sq += v[t] * v[t]; }
      if (has2) {
#pragma unroll
        for (int t = 0; t < 8; t++) d2 += v[t] * k2r[t];
      }
#pragma unroll
      for (int m = 1; m < 16; m <<= 1) {
        d1 += __shfl_xor(d1, m, 64);
        sq += __shfl_xor(sq, m, 64);
        if (has2) d2 += __shfl_xor(d2, m, 64);
      }
      if (lm == 0) {
        A.s1[brow + row] = d1;
        A.ssq[brow + row] = sq;
        if (has2) A.s2[brow + row] = d2;
      }
    }
  }
  if (A.rw[0] || A.rw[1] || A.rw[2]) {
    __syncthreads();
#pragma unroll
    for (int j = 0; j < 3; j++) {
      if (!A.rw[j]) continue;
#pragma unroll
      for (int t = 0; t < 8; t++) {
        racc[j][t] += __shfl_xor(racc[j][t], 16, 64);
        racc[j][t] += __shfl_xor(racc[j][t], 32, 64);
      }
      if (sub == 0) {
#pragma unroll
        for (int t = 0; t < 8; t++) atomicAdd(&rlds[j][m8 + t], racc[j][t]);
      }
    }
    __syncthreads();
    if (tid < kM) {
#pragma unroll
      for (int j = 0; j < 3; j++)
        if (A.rw[j]) atomicAdd(&A.ro[j][(size_t)b * kCatW + tid], rlds[j][tid]);
    }
  }
}

// ------- addressing: cosine score -> softmax -> +(1-g)w_prev -> shift -> sharpen -------
struct AddrArgs {
  const float* S[2];
  const float* R[2];
  const float* scal[2];
  const float* wprev[2];
  float* wout[2];
};

__global__ __launch_bounds__(256) void addressing(AddrArgs A) {
  const int b = blockIdx.x;
  const int hs = blockIdx.y;
  const float* S = A.S[hs] + (size_t)b * kN;
  const float* R = A.R[hs] + (size_t)b * kN;
  const float* sc = A.scal[hs] + b * 8;
  const float* wp = A.wprev[hs] + (size_t)b * kN;
  float* wo = A.wout[hs] + (size_t)b * kN;
  const float beta = sc[0], g = sc[1], r = sc[2];
  const float s0 = sc[3], s1 = sc[4], s2 = sc[5], kn = sc[6];
  __shared__ float wb[kN];
  __shared__ float red[4];
  const int tid = threadIdx.x;
  const int lane = tid & 63, wid = tid >> 6;
  float loc[16];
  float mx = -1e30f;
#pragma unroll
  for (int i = 0; i < 16; i++) {
    int n = tid + i * 256;
    float denom = fmaxf(sqrtf(R[n]) * kn, 1e-8f);
    float v = beta * S[n] / denom;
    loc[i] = v;
    mx = fmaxf(mx, v);
  }
#pragma unroll
  for (int m = 1; m < 64; m <<= 1) mx = fmaxf(mx, __shfl_xor(mx, m, 64));
  if (lane == 0) red[wid] = mx;
  __syncthreads();
  mx = fmaxf(fmaxf(red[0], red[1]), fmaxf(red[2], red[3]));
  float sum = 0.f;
#pragma unroll
  for (int i = 0; i < 16; i++) { loc[i] = expf(loc[i] - mx); sum += loc[i]; }
#pragma unroll
  for (int m = 1; m < 64; m <<= 1) sum += __shfl_xor(sum, m, 64);
  __syncthreads();
  if (lane == 0) red[wid] = sum;
  __syncthreads();
  sum = red[0] + red[1] + red[2] + red[3];
  const float inv = 1.f / sum;
  const float omg = 1.f - g;
#pragma unroll
  for (int i = 0; i < 16; i++) {
    int n = tid + i * 256;
    wb[n] = loc[i] * inv + omg * wp[n];
  }
  __syncthreads();
  float ssum = 0.f;
#pragma unroll
  for (int i = 0; i < 16; i++) {
    int n = tid + i * 256;
    float sh = s0 * wb[(n + kN - 1) & (kN - 1)] + s1 * wb[n] + s2 * wb[(n + 1) & (kN - 1)];
    float y = powf(sh, r);
    loc[i] = y;
    ssum += y;
  }
#pragma unroll
  for (int m = 1; m < 64; m <<= 1) ssum += __shfl_xor(ssum, m, 64);
  __syncthreads();
  if (lane == 0) red[wid] = ssum;
  __syncthreads();
  ssum = red[0] + red[1] + red[2] + red[3];
  const float invs = 1.f / (ssum + 1e-8f);
#pragma unroll
  for (int i = 0; i < 16; i++) {
    int n = tid + i * 256;
    wo[n] = loc[i] * invs;
  }
}

}  // namespace

extern "C" void kernel_launch(void* const* d_in, const int* in_sizes, int n_in,
                              void* d_out, int out_size, void* d_ws, size_t ws_size,
                              hipStream_t stream) {
  const float* x            = (const float*)d_in[0];
  const float* h_prev       = (const float*)d_in[1];
  const float* c_prev       = (const float*)d_in[2];
  const float* bank         = (const float*)d_in[3];
  const float* read_w_prev  = (const float*)d_in[4];
  const float* write_w_prev = (const float*)d_in[5];
  const float* W_ih         = (const float*)d_in[6];
  const float* W_hh         = (const float*)d_in[7];
  const float* b_ih         = (const float*)d_in[8];
  const float* b_hh         = (const float*)d_in[9];
  const float* read_W       = (const float*)d_in[10];
  const float* read_b       = (const float*)d_in[11];
  const float* write_W      = (const float*)d_in[12];
  const float* write_b      = (const float*)d_in[13];
  const float* out_W        = (const float*)d_in[14];
  const float* out_b        = (const float*)d_in[15];
  float* out = (float*)d_out;

  float* ws    = (float*)d_ws;
  float* gates = ws;                         // 64*2048
  float* praw  = gates + kB * kGates;        // 64*1600
  float* cat   = praw + kB * kPRow;          // 64*896
  float* kwb   = cat + kB * kCatW;           // 3*64*128
  float* krb   = kwb + 3 * kB * kM;
  float* evb   = krb + 3 * kB * kM;
  float* avb   = evb + 3 * kB * kM;
  float* scal  = avb + 3 * kB * kM;          // 6*64*8
  float* S1    = scal + 6 * kB * 8;          // 64*4096
  float* S2    = S1 + kWN;
  float* SSq   = S2 + kWN;
  float* wwv   = SSq + kWN;                  // 3*64*4096
  float* wrv   = wwv + 3 * kWN;              // 3*64*4096

  // ---- preamble: LSTM + projections + param split ----
  init_ws_k<<<512, 256, 0, stream>>>(gates, praw, cat, out, out_b);
  gemm_tn<<<dim3(kGates / 64, kE / 128), 256, 0, stream>>>(x, kE, W_ih, kE, gates, kGates, 0, kGates);
  gemm_tn<<<dim3(kGates / 64, kH / 128), 256, 0, stream>>>(h_prev, kH, W_hh, kH, gates, kGates, 0, kGates);
  lstm_nl<<<(kB * kH) / 256, 256, 0, stream>>>(gates, b_ih, b_hh, c_prev, cat);
  gemm_tn<<<dim3(19, kH / 128), 256, 0, stream>>>(cat + 3 * kM, kCatW, write_W, kH, praw, kPRow, 0, 1170);
  gemm_tn<<<dim3(7, kH / 128), 256, 0, stream>>>(cat + 3 * kM, kCatW, read_W, kH, praw, kPRow, 1170, 402);
  split_params<<<64, 128, 0, stream>>>(praw, write_b, read_b, kwb, krb, evb, avb, scal);

  // ---- P1: scores(bank0; kw0) ----
  {
    BankArgs p = {};
    p.bank = bank;
    p.k1 = kwb; p.s1 = S1; p.s2 = nullptr; p.ssq = SSq;
    bank_pass<0><<<dim3(16, kB), 256, 0, stream>>>(p);
  }
  {  // A1: ww0
    AddrArgs a = {};
    a.S[0] = S1; a.R[0] = SSq; a.scal[0] = scal + 0;
    a.wprev[0] = write_w_prev; a.wout[0] = wwv;
    a.S[1] = a.S[0]; a.R[1] = a.R[0]; a.scal[1] = a.scal[0]; a.wprev[1] = a.wprev[0]; a.wout[1] = a.wout[0];
    addressing<<<dim3(64, 1), 256, 0, stream>>>(a);
  }
  // ---- P2: scores(B0; kr0, kw1) ----
  {
    BankArgs p = {};
    p.bank = bank;
    p.cw[0] = wwv; p.ev[0] = evb; p.av[0] = avb;
    p.k1 = krb; p.k2 = kwb + kB * kM;
    p.s1 = S1; p.s2 = S2; p.ssq = SSq;
    bank_pass<1><<<dim3(16, kB), 256, 0, stream>>>(p);
  }
  {  // A2: wr0, ww1
    AddrArgs a = {};
    a.S[0] = S1; a.R[0] = SSq; a.scal[0] = scal + (size_t)3 * kB * 8;
    a.wprev[0] = read_w_prev; a.wout[0] = wrv;
    a.S[1] = S2; a.R[1] = SSq; a.scal[1] = scal + (size_t)1 * kB * 8;
    a.wprev[1] = write_w_prev + kWN; a.wout[1] = wwv + kWN;
    addressing<<<dim3(64, 2), 256, 0, stream>>>(a);
  }
  // ---- P3: read0 from B0; scores(B1; kr1, kw2) ----
  {
    BankArgs p = {};
    p.bank = bank;
    p.cw[0] = wwv;        p.ev[0] = evb;            p.av[0] = avb;
    p.cw[1] = wwv + kWN;  p.ev[1] = evb + kB * kM;  p.av[1] = avb + kB * kM;
    p.rw[0] = wrv; p.ro[0] = cat;           // read0 -> cat[:,0:128]
    p.k1 = krb + kB * kM; p.k2 = kwb + 2 * kB * kM;
    p.s1 = S1; p.s2 = S2; p.ssq = SSq;
    bank_pass<2><<<dim3(16, kB), 256, 0, stream>>>(p);
  }
  {  // A3: wr1, ww2
    AddrArgs a = {};
    a.S[0] = S1; a.R[0] = SSq; a.scal[0] = scal + (size_t)4 * kB * 8;
    a.wprev[0] = read_w_prev + kWN; a.wout[0] = wrv + kWN;
    a.S[1] = S2; a.R[1] = SSq; a.scal[1] = scal + (size_t)2 * kB * 8;
    a.wprev[1] = write_w_prev + 2 * kWN; a.wout[1] = wwv + 2 * kWN;
    addressing<<<dim3(64, 2), 256, 0, stream>>>(a);
  }
  // ---- P4: scores(B2; kr2) ----
  {
    BankArgs p = {};
    p.bank = bank;
    p.cw[0] = wwv;           p.ev[0] = evb;                p.av[0] = avb;
    p.cw[1] = wwv + kWN;     p.ev[1] = evb + kB * kM;      p.av[1] = avb + kB * kM;
    p.cw[2] = wwv + 2 * kWN; p.ev[2] = evb + 2 * kB * kM;  p.av[2] = avb + 2 * kB * kM;
    p.k1 = krb + 2 * kB * kM;
    p.s1 = S1; p.s2 = nullptr; p.ssq = SSq;
    bank_pass<3><<<dim3(16, kB), 256, 0, stream>>>(p);
  }
  {  // A4: wr2
    AddrArgs a = {};
    a.S[0] = S1; a.R[0] = SSq; a.scal[0] = scal + (size_t)5 * kB * 8;
    a.wprev[0] = read_w_prev + 2 * kWN; a.wout[0] = wrv + 2 * kWN;
    a.S[1] = a.S[0]; a.R[1] = a.R[0]; a.scal[1] = a.scal[0]; a.wprev[1] = a.wprev[0]; a.wout[1] = a.wout[0];
    addressing<<<dim3(64, 1), 256, 0, stream>>>(a);
  }
  // ---- P5: read1 from B1, read2 from B2 ----
  {
    BankArgs p = {};
    p.bank = bank;
    p.cw[0] = wwv;           p.ev[0] = evb;                p.av[0] = avb;
    p.cw[1] = wwv + kWN;     p.ev[1] = evb + kB * kM;      p.av[1] = avb + kB * kM;
    p.cw[2] = wwv + 2 * kWN; p.ev[2] = evb + 2 * kB * kM;  p.av[2] = avb + 2 * kB * kM;
    p.rw[1] = wrv + kWN;     p.ro[1] = cat + kM;       // read1 -> cat[:,128:256]
    p.rw[2] = wrv + 2 * kWN; p.ro[2] = cat + 2 * kM;   // read2 -> cat[:,256:384]
    p.s1 = nullptr; p.s2 = nullptr; p.ssq = nullptr;
    bank_pass<3><<<dim3(16, kB), 256, 0, stream>>>(p);
  }
  // ---- output projection: out = cat @ out_W.T + out_b (bias from init) ----
  gemm_tn<<<dim3(kO / 64, kCatW / 128), 256, 0, stream>>>(cat, kCatW, out_W, kCatW, out, kO, 0, kO);

  (void)in_sizes; (void)n_in; (void)out_size; (void)ws_size;
}